// Round 1
// baseline (376.281 us; speedup 1.0000x reference)
//
#include <hip/hip_runtime.h>

// Problem constants (match reference)
#define H_  1024
#define W_  2048
#define HP  1026            // H+2
#define WP  2050            // W+2
#define GRID_F (HP*WP)      // 2,103,300 floats = 8.41 MB
#define STATS_OFF 2103360   // 64-aligned, 54 floats of moment accumulators
#define SCALE_OFF 2103424   // 64 floats
#define SHIFT_OFF 2103488   // 64 floats

// ---------------------------------------------------------------- scatter
__global__ __launch_bounds__(256) void scatter_k(
    const float* __restrict__ feats, const int2* __restrict__ coords,
    float* __restrict__ grid, int N)
{
    int i = blockIdx.x * 256 + threadIdx.x;
    if (i >= N) return;
    int2 c = coords[i];                       // c.x = y, c.y = x
    grid[(c.x + 1) * WP + (c.y + 1)] = feats[i];
}

// ---------------------------------------------------------------- stats
// Accumulate s[k] = sum_i nb[i][k]  (9)  and upper-tri second moments
// M[k][l] = sum_i nb[i][k]*nb[i][l] (45) -> 54 floats total.
__global__ __launch_bounds__(256) void stats_k(
    const float* __restrict__ grid, const int2* __restrict__ coords,
    float* __restrict__ stats, int N)
{
    const int off[9] = {-WP-1, -WP, -WP+1, -1, 0, 1, WP-1, WP, WP+1};
    float acc[54];
    #pragma unroll
    for (int j = 0; j < 54; ++j) acc[j] = 0.f;

    int stride = gridDim.x * blockDim.x;
    for (int i = blockIdx.x * blockDim.x + threadIdx.x; i < N; i += stride) {
        int2 c = coords[i];
        int base = (c.x + 1) * WP + (c.y + 1);
        float p[9];
        #pragma unroll
        for (int k = 0; k < 9; ++k) p[k] = grid[base + off[k]];
        #pragma unroll
        for (int k = 0; k < 9; ++k) acc[k] += p[k];
        int t = 9;
        #pragma unroll
        for (int k = 0; k < 9; ++k)
            #pragma unroll
            for (int l = k; l < 9; ++l) acc[t++] += p[k] * p[l];
    }

    // wave(64) shuffle reduce -> LDS per-wave partials -> one atomic/value
    __shared__ float part[4][54];
    int wave = threadIdx.x >> 6, lane = threadIdx.x & 63;
    #pragma unroll
    for (int j = 0; j < 54; ++j) {
        float v = acc[j];
        #pragma unroll
        for (int d = 32; d > 0; d >>= 1) v += __shfl_down(v, d, 64);
        if (lane == 0) part[wave][j] = v;
    }
    __syncthreads();
    if (threadIdx.x < 54) {
        float v = part[0][threadIdx.x] + part[1][threadIdx.x]
                + part[2][threadIdx.x] + part[3][threadIdx.x];
        atomicAdd(&stats[threadIdx.x], v);
    }
}

// ---------------------------------------------------------------- finalize
// mean[c] = (s/N) . W[:,c];  E2[c] = W[:,c]^T (M/N) W[:,c];  var = E2 - mean^2
// Fold BN into out*scale + shift.
__global__ void finalize_k(
    const float* __restrict__ stats, const float* __restrict__ w,
    const float* __restrict__ gamma, const float* __restrict__ beta,
    float* __restrict__ scale, float* __restrict__ shift, int N)
{
    int c = threadIdx.x;                      // 0..63
    float invN = 1.0f / (float)N;
    float wc[9];
    #pragma unroll
    for (int k = 0; k < 9; ++k) wc[k] = w[k * 64 + c];
    float mean = 0.f;
    #pragma unroll
    for (int k = 0; k < 9; ++k) mean += stats[k] * invN * wc[k];
    float e2 = 0.f;
    int t = 9;
    #pragma unroll
    for (int k = 0; k < 9; ++k)
        #pragma unroll
        for (int l = k; l < 9; ++l) {
            float mm = stats[t++] * invN;
            e2 += (k == l ? 1.f : 2.f) * wc[k] * wc[l] * mm;
        }
    float var = e2 - mean * mean;
    float sc = gamma[c] * rsqrtf(var + 1e-5f);
    scale[c] = sc;
    shift[c] = beta[c] - mean * sc;
}

// ---------------------------------------------------------------- output
// 64 points / block. Stage 9 gathers per point + weights + scale/shift in
// LDS, then emit float4 stores with lane-consecutive global addresses:
// out4[blk*1024 + tid + r*256]  (1 KB contiguous per store instruction).
__global__ __launch_bounds__(256) void out_k(
    const float* __restrict__ grid, const int2* __restrict__ coords,
    const float* __restrict__ w, const float* __restrict__ scale,
    const float* __restrict__ shift, float* __restrict__ out, int N)
{
    __shared__ float w_s[576];
    __shared__ float nb_s[9][64];
    __shared__ int   base_s[64];
    __shared__ float sc_s[64], sh_s[64];

    int t  = threadIdx.x;
    int p0 = blockIdx.x * 64;

    w_s[t]       = w[t];
    w_s[t + 256] = w[t + 256];
    if (t < 64) {
        w_s[t + 512] = w[t + 512];
        sc_s[t] = scale[t];
        sh_s[t] = shift[t];
        int p  = p0 + t;
        int2 c = (p < N) ? coords[p] : make_int2(0, 0);
        base_s[t] = (c.x + 1) * WP + (c.y + 1);
    }
    __syncthreads();

    const int off[9] = {-WP-1, -WP, -WP+1, -1, 0, 1, WP-1, WP, WP+1};
    #pragma unroll
    for (int j = t; j < 576; j += 256) {       // 576 = 9 offsets * 64 points
        int k = j >> 6, pt = j & 63;
        int p = p0 + pt;
        nb_s[k][pt] = (p < N) ? grid[base_s[pt] + off[k]] : 0.f;
    }
    __syncthreads();

    const float4* w4   = (const float4*)w_s;   // [9][16] float4 chunks
    float4*       out4 = (float4*)out;
    long base16 = (long)blockIdx.x * 1024;     // block covers 1024 float4s
    long lim16  = (long)N * 16;

    #pragma unroll
    for (int r = 0; r < 4; ++r) {
        int idx = t + r * 256;                 // 0..1023
        int pt  = idx >> 4;                    // point within block
        int q   = idx & 15;                    // channel quad (4 channels)
        float4 acc = {0.f, 0.f, 0.f, 0.f};
        #pragma unroll
        for (int k = 0; k < 9; ++k) {
            float  pk = nb_s[k][pt];
            float4 wv = w4[k * 16 + q];
            acc.x += pk * wv.x; acc.y += pk * wv.y;
            acc.z += pk * wv.z; acc.w += pk * wv.w;
        }
        int c0 = q * 4;
        acc.x = fmaxf(fmaf(acc.x, sc_s[c0+0], sh_s[c0+0]), 0.f);
        acc.y = fmaxf(fmaf(acc.y, sc_s[c0+1], sh_s[c0+1]), 0.f);
        acc.z = fmaxf(fmaf(acc.z, sc_s[c0+2], sh_s[c0+2]), 0.f);
        acc.w = fmaxf(fmaf(acc.w, sc_s[c0+3], sh_s[c0+3]), 0.f);
        long gi = base16 + idx;
        if (gi < lim16) out4[gi] = acc;
    }
}

// ---------------------------------------------------------------- launch
extern "C" void kernel_launch(void* const* d_in, const int* in_sizes, int n_in,
                              void* d_out, int out_size, void* d_ws, size_t ws_size,
                              hipStream_t stream)
{
    const float* feats  = (const float*)d_in[0];
    const float* weight = (const float*)d_in[1];   // [9][1][64]
    const float* gamma  = (const float*)d_in[2];
    const float* beta   = (const float*)d_in[3];
    const int2*  coords = (const int2*)d_in[4];    // [N][2] (y,x)
    float*       out    = (float*)d_out;
    int N = in_sizes[0];                           // C_IN == 1

    float* ws    = (float*)d_ws;
    float* grid  = ws;
    float* stats = ws + STATS_OFF;
    float* scale = ws + SCALE_OFF;
    float* shift = ws + SHIFT_OFF;

    // zero grid + stats accumulators (d_ws is poisoned 0xAA before each call)
    hipMemsetAsync(d_ws, 0, (size_t)(STATS_OFF + 64) * sizeof(float), stream);

    scatter_k <<<(N + 255) / 256, 256, 0, stream>>>(feats, coords, grid, N);
    stats_k   <<<512, 256, 0, stream>>>(grid, coords, stats, N);
    finalize_k<<<1, 64, 0, stream>>>(stats, weight, gamma, beta, scale, shift, N);
    out_k     <<<(N + 63) / 64, 256, 0, stream>>>(grid, coords, weight, scale, shift, out, N);
}

// Round 3
// 363.613 us; speedup vs baseline: 1.0348x; 1.0348x over previous
//
#include <hip/hip_runtime.h>

// Problem constants (match reference)
#define H_  1024
#define W_  2048
#define HP  1026                 // H+2
#define WP  2050                 // W+2
#define GRID_F (HP*WP)           // 2,103,300 cells = 8.41 MB fp32

// ws layout (floats)
#define IDX_OFF   2103360        // int grid, 64-aligned
#define STATS_OFF 4206720        // 54 moment accumulators
#define SCALE_OFF 4206784
#define SHIFT_OFF 4206848

typedef float fvec4 __attribute__((ext_vector_type(4)));

// ---------------------------------------------------------------- scatter
// Write feature value AND point-index(+1) into dense padded grids.
__global__ __launch_bounds__(256) void scatter_k(
    const float* __restrict__ feats, const int2* __restrict__ coords,
    float* __restrict__ grid, int* __restrict__ idxg, int N)
{
    int i = blockIdx.x * 256 + threadIdx.x;
    if (i >= N) return;
    int2 c = coords[i];                       // c.x = y, c.y = x
    int cell = (c.x + 1) * WP + (c.y + 1);
    grid[cell] = feats[i];
    idxg[cell] = i + 1;
}

// ---------------------------------------------------------------- stats
// Dense row-order pass: s[k] = sum over active cells of window val k (9),
// M[k][l] upper-tri second moments (45) -> 54 floats. All loads coalesced.
__global__ __launch_bounds__(256) void stats_dense_k(
    const float* __restrict__ grid, const int* __restrict__ idxg,
    float* __restrict__ stats)
{
    const int off[9] = {-WP-1, -WP, -WP+1, -1, 0, 1, WP-1, WP, WP+1};
    float acc[54];
    #pragma unroll
    for (int j = 0; j < 54; ++j) acc[j] = 0.f;

    int stride = gridDim.x * blockDim.x;
    for (int c = blockIdx.x * blockDim.x + threadIdx.x; c < GRID_F; c += stride) {
        if (idxg[c] > 0) {                    // active center
            float p[9];
            #pragma unroll
            for (int k = 0; k < 9; ++k) p[k] = grid[c + off[k]];
            #pragma unroll
            for (int k = 0; k < 9; ++k) acc[k] += p[k];
            int t = 9;
            #pragma unroll
            for (int k = 0; k < 9; ++k)
                #pragma unroll
                for (int l = k; l < 9; ++l) acc[t++] += p[k] * p[l];
        }
    }

    __shared__ float part[4][54];
    int wave = threadIdx.x >> 6, lane = threadIdx.x & 63;
    #pragma unroll
    for (int j = 0; j < 54; ++j) {
        float v = acc[j];
        #pragma unroll
        for (int d = 32; d > 0; d >>= 1) v += __shfl_down(v, d, 64);
        if (lane == 0) part[wave][j] = v;
    }
    __syncthreads();
    if (threadIdx.x < 54) {
        float v = part[0][threadIdx.x] + part[1][threadIdx.x]
                + part[2][threadIdx.x] + part[3][threadIdx.x];
        atomicAdd(&stats[threadIdx.x], v);
    }
}

// ---------------------------------------------------------------- finalize
__global__ void finalize_k(
    const float* __restrict__ stats, const float* __restrict__ w,
    const float* __restrict__ gamma, const float* __restrict__ beta,
    float* __restrict__ scale, float* __restrict__ shift, int N)
{
    int c = threadIdx.x;                      // 0..63
    float invN = 1.0f / (float)N;
    float wc[9];
    #pragma unroll
    for (int k = 0; k < 9; ++k) wc[k] = w[k * 64 + c];
    float mean = 0.f;
    #pragma unroll
    for (int k = 0; k < 9; ++k) mean += stats[k] * invN * wc[k];
    float e2 = 0.f;
    int t = 9;
    #pragma unroll
    for (int k = 0; k < 9; ++k)
        #pragma unroll
        for (int l = k; l < 9; ++l) {
            float mm = stats[t++] * invN;
            e2 += (k == l ? 1.f : 2.f) * wc[k] * wc[l] * mm;
        }
    float var = e2 - mean * mean;
    float sc = gamma[c] * rsqrtf(var + 1e-5f);
    scale[c] = sc;
    shift[c] = beta[c] - mean * sc;
}

// ---------------------------------------------------------------- output
// Dense tile pass: 256 consecutive cells / block. Compact active cells to
// LDS, gather windows from an L1-resident band, compute 64 channels, store
// 256B-contiguous per point (16-lane groups emit float4) nontemporally.
__global__ __launch_bounds__(256) void out_dense_k(
    const float* __restrict__ grid, const int* __restrict__ idxg,
    const float* __restrict__ w, const float* __restrict__ scale,
    const float* __restrict__ shift, float* __restrict__ out)
{
    __shared__ float w_s[576];
    __shared__ float sc_s[64], sh_s[64];
    __shared__ float nb_s[9][256];
    __shared__ int   cell_s[256];
    __shared__ int   oidx_s[256];
    __shared__ int   cnt;

    int t = threadIdx.x;
    if (t == 0) cnt = 0;
    w_s[t]       = w[t];
    w_s[t + 256] = w[t + 256];
    if (t < 64) {
        w_s[t + 512] = w[t + 512];
        sc_s[t] = scale[t];
        sh_s[t] = shift[t];
    }
    __syncthreads();                           // cnt=0 visible

    int c = blockIdx.x * 256 + t;
    if (c < GRID_F) {
        int idx = idxg[c];
        if (idx > 0) {
            int p = atomicAdd(&cnt, 1);
            cell_s[p] = c;
            oidx_s[p] = idx - 1;
        }
    }
    __syncthreads();
    int M = cnt;
    if (M == 0) return;

    const int off[9] = {-WP-1, -WP, -WP+1, -1, 0, 1, WP-1, WP, WP+1};
    if (t < M) {
        int base = cell_s[t];
        #pragma unroll
        for (int k = 0; k < 9; ++k) nb_s[k][t] = grid[base + off[k]];
    }
    __syncthreads();

    const fvec4* w4   = (const fvec4*)w_s;     // [9][16]
    fvec4*       out4 = (fvec4*)out;

    for (int u = t; u < 16 * M; u += 256) {
        int pt = u >> 4;                       // compacted point
        int q  = u & 15;                       // channel quad
        fvec4 acc = {0.f, 0.f, 0.f, 0.f};
        #pragma unroll
        for (int k = 0; k < 9; ++k) {
            float pk = nb_s[k][pt];
            fvec4 wv = w4[k * 16 + q];
            acc.x = fmaf(pk, wv.x, acc.x);
            acc.y = fmaf(pk, wv.y, acc.y);
            acc.z = fmaf(pk, wv.z, acc.z);
            acc.w = fmaf(pk, wv.w, acc.w);
        }
        int c0 = q * 4;
        acc.x = fmaxf(fmaf(acc.x, sc_s[c0+0], sh_s[c0+0]), 0.f);
        acc.y = fmaxf(fmaf(acc.y, sc_s[c0+1], sh_s[c0+1]), 0.f);
        acc.z = fmaxf(fmaf(acc.z, sc_s[c0+2], sh_s[c0+2]), 0.f);
        acc.w = fmaxf(fmaf(acc.w, sc_s[c0+3], sh_s[c0+3]), 0.f);
        __builtin_nontemporal_store(acc, &out4[(long)oidx_s[pt] * 16 + q]);
    }
}

// ---------------------------------------------------------------- launch
extern "C" void kernel_launch(void* const* d_in, const int* in_sizes, int n_in,
                              void* d_out, int out_size, void* d_ws, size_t ws_size,
                              hipStream_t stream)
{
    const float* feats  = (const float*)d_in[0];
    const float* weight = (const float*)d_in[1];   // [9][1][64]
    const float* gamma  = (const float*)d_in[2];
    const float* beta   = (const float*)d_in[3];
    const int2*  coords = (const int2*)d_in[4];    // [N][2] (y,x)
    float*       out    = (float*)d_out;
    int N = in_sizes[0];                           // C_IN == 1

    float* ws    = (float*)d_ws;
    float* grid  = ws;
    int*   idxg  = (int*)(ws + IDX_OFF);
    float* stats = ws + STATS_OFF;
    float* scale = ws + SCALE_OFF;
    float* shift = ws + SHIFT_OFF;

    // zero grid + idx grid + stats accumulators (ws is poisoned 0xAA)
    (void)hipMemsetAsync(d_ws, 0, (size_t)(STATS_OFF + 64) * sizeof(float), stream);

    scatter_k    <<<(N + 255) / 256, 256, 0, stream>>>(feats, coords, grid, idxg, N);
    stats_dense_k<<<1024, 256, 0, stream>>>(grid, idxg, stats);
    finalize_k   <<<1, 64, 0, stream>>>(stats, weight, gamma, beta, scale, shift, N);
    out_dense_k  <<<(GRID_F + 255) / 256, 256, 0, stream>>>(grid, idxg, weight, scale, shift, out);
}